// Round 2
// baseline (382.756 us; speedup 1.0000x reference)
//
#include <hip/hip_runtime.h>
#include <hip/hip_bf16.h>
#include <stdint.h>

// Problem constants (reference: B,TQ,TK,D,DV = 8,2048,2048,1024,1024)
#define B_  8
#define TQ_ 2048
#define TK_ 2048
#define D_  1024
#define DV_ 1024

typedef __attribute__((ext_vector_type(8))) short  short8;
typedef __attribute__((ext_vector_type(4))) float  floatx4;

__device__ __forceinline__ void async_copy16(const void* g, void* l) {
  // 16B-per-lane global->LDS DMA. LDS dest is wave-uniform base + lane*16.
  __builtin_amdgcn_global_load_lds(
      (const __attribute__((address_space(1))) unsigned int*)g,
      (__attribute__((address_space(3))) unsigned int*)l,
      16, 0, 0);
}

__device__ __forceinline__ ushort f2bf(float f) {
  union { __hip_bfloat16 b; ushort u; } cv;
  cv.b = __float2bfloat16(f);
  return cv.u;
}

__device__ __forceinline__ float bf2f(ushort u) {
  union { ushort u; __hip_bfloat16 b; } cv;
  cv.u = u;
  return __bfloat162float(cv.b);
}

// ---------------- fused prep kernel (unchanged, verified) ----------------
__device__ __forceinline__ void transpose_body(const float* __restrict__ in,
                                               ushort* __restrict__ out,
                                               int R, int C, int r0, int c0,
                                               float (*tile)[65]) {
  const int t = threadIdx.x;
  {
    const int row = t >> 4, col = (t & 15) * 4;
    #pragma unroll
    for (int ro = 0; ro < 4; ro++) {
      const float4 f = *(const float4*)&in[(size_t)(r0 + ro * 16 + row) * C + c0 + col];
      tile[ro * 16 + row][col + 0] = f.x;
      tile[ro * 16 + row][col + 1] = f.y;
      tile[ro * 16 + row][col + 2] = f.z;
      tile[ro * 16 + row][col + 3] = f.w;
    }
  }
  __syncthreads();
  {
    const int c = t >> 4, rg = (t & 15) * 4;
    #pragma unroll
    for (int ro = 0; ro < 4; ro++) {
      const int cc = ro * 16 + c;
      ushort4 o;
      o.x = f2bf(tile[rg + 0][cc]);
      o.y = f2bf(tile[rg + 1][cc]);
      o.z = f2bf(tile[rg + 2][cc]);
      o.w = f2bf(tile[rg + 3][cc]);
      *(ushort4*)&out[(size_t)(c0 + cc) * R + r0 + rg] = o;
    }
  }
}

__global__ void prep(const float* __restrict__ q, const float* __restrict__ k,
                     const float* __restrict__ v, ushort* __restrict__ qb,
                     ushort* __restrict__ ktb, ushort* __restrict__ vtb) {
  __shared__ float tile[64][65];
  const int task = blockIdx.z >> 3;
  const int z    = blockIdx.z & 7;
  if (task == 0) {
    const float4* in  = (const float4*)(q + (size_t)z * TQ_ * D_);
    ushort4*      oup = (ushort4*)(qb + (size_t)z * TQ_ * D_);
    const int i0 = (blockIdx.y * 32 + blockIdx.x) * 1024 + threadIdx.x;
    #pragma unroll
    for (int it = 0; it < 4; it++) {
      const int i = i0 + it * 256;
      float4 f = in[i];
      ushort4 o;
      o.x = f2bf(f.x); o.y = f2bf(f.y); o.z = f2bf(f.z); o.w = f2bf(f.w);
      oup[i] = o;
    }
  } else if (task == 1) {
    transpose_body(k + (size_t)z * D_ * TK_, ktb + (size_t)z * TK_ * D_,
                   D_, TK_, blockIdx.y * 64, blockIdx.x * 64, tile);
  } else {
    transpose_body(v + (size_t)z * TK_ * DV_, vtb + (size_t)z * DV_ * TK_,
                   TK_, DV_, blockIdx.x * 64, blockIdx.y * 64, tile);
  }
}

// ---------------- 256x256-tile deep-pipeline GEMM core ----------------
// BM=BN=256, BK=64, 512 thr = 8 waves (2 wm x 4 wn), per-wave C = 128x64 =
// acc[8][4] of mfma_f32_16x16x32_bf16.
// Staged panels are split along K into two k-halves (kh0 = k 0..31, kh1 =
// 32..63), each 256 rows x 64B. LDS 128 KiB:
//   A: buf*32768 + kh*16384 + row*64 + slot*16          (@0)
//   B: 65536 + same                                      (@64KiB)
// Swizzle (round-0-verified, conflicts==0): slot s of row r holds global
// chunk s ^ ((r>>1)&3); inverse pre-applied on the global source address so
// the LDS dest stays linear (global_load_lds requirement).
// Phase = (row-half mh, k-half ks); per tile tt:
//  P1 (mh0,ks0): read a[4]+b0[4]; stage A-kh1(tt+1)           | bar | 16 MFMA | bar
//  P2 (mh1,ks0): read a[4];       stage B-kh0(tt+2); vmcnt(10)| bar | 16 MFMA | bar
//  P3 (mh0,ks1): read a[4]+b1[4]; stage A-kh0(tt+2)           | bar | 16 MFMA | bar
//  P4 (mh1,ks1): read a[4];       stage B-kh1(tt+2); vmcnt(8) | bar | 16 MFMA | bar
// Region safety: B-kh0(tt) fully read at P1 (b0 kept in regs) -> free P2;
// A-kh0(tt) read P1,P2 -> free P3; B-kh1(tt) read P3 -> free P4; A-kh1(tt+1)
// region (= A(tt-1) kh1) free since tt-1 P4. All stage targets barrier-safe.
// Drain FIFO arithmetic (2 loads per half): vmcnt(10)@P2 retires through
// tt-1 P1 (A-kh1(tt) ready for P3); vmcnt(8)@P4 retires through tt-1 P4
// (A-kh0/B-kh0(tt+1) ready for tt+1 P1). Min issue->drain lead = 4 phases,
// max 6 -- HBM latency fully covered. Never vmcnt(0) in the loop.
// Tail: stages wrap k modulo KDIM (garbage into already-dead regions) so
// load counts stay uniform and the vmcnt constants remain exact.

#define WG_BARRIER() do { asm volatile("" ::: "memory");        \
                          __builtin_amdgcn_s_barrier();         \
                          asm volatile("" ::: "memory"); } while (0)
#define VMCNT(n) asm volatile("s_waitcnt vmcnt(" #n ")" ::: "memory")

template <int KDIM>
__device__ __forceinline__ void gemm_core8(const ushort* __restrict__ Ap,
                                           const ushort* __restrict__ Bp,
                                           char* lds, int bm0, int bn0,
                                           floatx4 (&acc)[8][4]) {
  const int t    = threadIdx.x;
  const int lane = t & 63;
  const int w    = t >> 6;
  const int wm   = w >> 2, wn = w & 3;
  const int lc   = lane & 15, q = lane >> 4;
  const int offq = (q ^ ((lc >> 1) & 3)) * 16;   // swizzled 16B slot in 64B row
  constexpr int NT = KDIM / 64;

  // per-thread LDS read bases (row term includes wm/wn band + lc)
  const char* Abase = lds + (wm * 128 + lc) * 64 + offq;
  const char* Bbase = lds + 65536 + (wn * 64 + lc) * 64 + offq;

  // per-thread hoisted global stage bases: row = t>>2, pre-swizzled chunk
  const int srow = t >> 2;
  const int sch  = (t & 3) ^ ((t >> 3) & 3);
  const ushort* gA = Ap + (size_t)(bm0 + srow) * KDIM + sch * 8;
  const ushort* gB = Bp + (size_t)(bn0 + srow) * KDIM + sch * 8;

  auto stageA = [&](int buf, int kh, int kb) {
    char* d = lds + buf * 32768 + kh * 16384 + t * 16;
    async_copy16(gA + kb, d);
    async_copy16(gA + (size_t)128 * KDIM + kb, d + 8192);
  };
  auto stageB = [&](int buf, int kh, int kb) {
    char* d = lds + 65536 + buf * 32768 + kh * 16384 + t * 16;
    async_copy16(gB + kb, d);
    async_copy16(gB + (size_t)128 * KDIM + kb, d + 8192);
  };

  #pragma unroll
  for (int mi = 0; mi < 8; ++mi)
    #pragma unroll
    for (int ni = 0; ni < 4; ++ni)
      acc[mi][ni] = (floatx4){0.f, 0.f, 0.f, 0.f};

  // prologue: 7 halves in steady-state FIFO order, then drain the 2 oldest
  stageB(0, 0, 0);   stageA(0, 0, 0);
  stageB(0, 1, 32);  stageA(0, 1, 32);
  stageB(1, 0, 64);  stageA(1, 0, 64);
  stageB(1, 1, 96);
  VMCNT(10);
  WG_BARRIER();

  // rolling k element-offsets for the 4 stage slots (wrap keeps counts uniform)
  int kA1 = 96, kB0 = 128, kA0 = 128, kB1 = 160;

  short8 a[4], b0[4], b1[4];
  #pragma unroll 2
  for (int tt = 0; tt < NT; ++tt) {
    const int cur = tt & 1, nxt = cur ^ 1;
    const char* A  = Abase + cur * 32768;
    const char* Bq = Bbase + cur * 32768;

    // ---- P1: (mh0, ks0) ----
    #pragma unroll
    for (int j = 0; j < 4; ++j) a[j]  = *(const short8*)(A + j * 1024);
    #pragma unroll
    for (int i = 0; i < 4; ++i) b0[i] = *(const short8*)(Bq + i * 1024);
    stageA(nxt, 1, kA1); kA1 += 64; if (kA1 >= KDIM) kA1 -= KDIM;
    WG_BARRIER();
    __builtin_amdgcn_s_setprio(1);
    #pragma unroll
    for (int j = 0; j < 4; ++j)
      #pragma unroll
      for (int i = 0; i < 4; ++i)
        acc[j][i] = __builtin_amdgcn_mfma_f32_16x16x32_bf16(a[j], b0[i], acc[j][i], 0, 0, 0);
    __builtin_amdgcn_s_setprio(0);
    WG_BARRIER();

    // ---- P2: (mh1, ks0) ----
    #pragma unroll
    for (int j = 0; j < 4; ++j) a[j] = *(const short8*)(A + 4096 + j * 1024);
    stageB(cur, 0, kB0); kB0 += 64; if (kB0 >= KDIM) kB0 -= KDIM;
    VMCNT(10);
    WG_BARRIER();
    __builtin_amdgcn_s_setprio(1);
    #pragma unroll
    for (int j = 0; j < 4; ++j)
      #pragma unroll
      for (int i = 0; i < 4; ++i)
        acc[4 + j][i] = __builtin_amdgcn_mfma_f32_16x16x32_bf16(a[j], b0[i], acc[4 + j][i], 0, 0, 0);
    __builtin_amdgcn_s_setprio(0);
    WG_BARRIER();

    // ---- P3: (mh0, ks1) ----
    #pragma unroll
    for (int j = 0; j < 4; ++j) a[j]  = *(const short8*)(A + 16384 + j * 1024);
    #pragma unroll
    for (int i = 0; i < 4; ++i) b1[i] = *(const short8*)(Bq + 16384 + i * 1024);
    stageA(cur, 0, kA0); kA0 += 64; if (kA0 >= KDIM) kA0 -= KDIM;
    WG_BARRIER();
    __builtin_amdgcn_s_setprio(1);
    #pragma unroll
    for (int j = 0; j < 4; ++j)
      #pragma unroll
      for (int i = 0; i < 4; ++i)
        acc[j][i] = __builtin_amdgcn_mfma_f32_16x16x32_bf16(a[j], b1[i], acc[j][i], 0, 0, 0);
    __builtin_amdgcn_s_setprio(0);
    WG_BARRIER();

    // ---- P4: (mh1, ks1) ----
    #pragma unroll
    for (int j = 0; j < 4; ++j) a[j] = *(const short8*)(A + 16384 + 4096 + j * 1024);
    stageB(cur, 1, kB1); kB1 += 64; if (kB1 >= KDIM) kB1 -= KDIM;
    VMCNT(8);
    WG_BARRIER();
    __builtin_amdgcn_s_setprio(1);
    #pragma unroll
    for (int j = 0; j < 4; ++j)
      #pragma unroll
      for (int i = 0; i < 4; ++i)
        acc[4 + j][i] = __builtin_amdgcn_mfma_f32_16x16x32_bf16(a[j], b1[i], acc[4 + j][i], 0, 0, 0);
    __builtin_amdgcn_s_setprio(0);
    WG_BARRIER();
  }
  VMCNT(0);   // retire tail garbage DMAs before LDS goes out of scope
}

// XCD-chunked bijective remap (nwg % 8 == 0): XCD c owns one contiguous
// chunk of virtual block ids -> here one whole batch per XCD, so each XCD's
// L2 holds only its own batch's A/B panels.
__device__ __forceinline__ void xcd_coords(int& bx, int& by, int& bz) {
  const int gx = gridDim.x, gy = gridDim.y;
  int lidx = blockIdx.x + gx * (blockIdx.y + gy * blockIdx.z);
  const int nwg = gx * gy * gridDim.z;
  lidx = (lidx & 7) * (nwg >> 3) + (lidx >> 3);
  bx = lidx % gx;
  const int byz = lidx / gx;
  by = byz % gy;
  bz = byz / gy;
}

// GEMM1: P = exp(tanh(Q K + b)) in bf16; row sums of the bf16-rounded P via
// per-16-lane shuffle reduce + one atomicAdd per row-fragment.
__global__ __launch_bounds__(512, 2)
void gemm_qk(const ushort* __restrict__ Q, const ushort* __restrict__ Kt,
             const float* __restrict__ bias, ushort* __restrict__ P,
             float* __restrict__ lsum) {
  __shared__ short8 ldsv[8192];       // 128 KiB
  char* lds = (char*)ldsv;
  int bx, by, z;
  xcd_coords(bx, by, z);
  const int bm0 = by * 256;
  const int bn0 = bx * 256;

  floatx4 acc[8][4];
  gemm_core8<D_>(Q + (size_t)z * TQ_ * D_, Kt + (size_t)z * TK_ * D_,
                 lds, bm0, bn0, acc);

  const int lane = threadIdx.x & 63;
  const int w    = threadIdx.x >> 6;
  const int wm   = w >> 2, wn = w & 3;
  const int lc   = lane & 15, q = lane >> 4;
  ushort* Pb = P + (size_t)z * TQ_ * TK_;
  float*  lz = lsum + z * TQ_;

  #pragma unroll
  for (int mi = 0; mi < 8; ++mi) {
    const int grow = bm0 + wm * 128 + mi * 16 + (q << 2);
    float rs[4] = {0.f, 0.f, 0.f, 0.f};
    #pragma unroll
    for (int ni = 0; ni < 4; ++ni) {
      const int gcol = bn0 + wn * 64 + ni * 16 + lc;
      const float bj = bias[gcol];
      #pragma unroll
      for (int r = 0; r < 4; ++r) {
        float s = acc[mi][ni][r] + bj;
        // tanh(s) = 1 - 2/(e^{2s}+1); safe at +/-inf. exp(tanh) in [0.37,2.72]
        // => softmax needs no max subtraction.
        float tnh = 1.f - 2.f / (__expf(2.f * s) + 1.f);
        float p   = __expf(tnh);
        ushort pu = f2bf(p);
        Pb[(size_t)(grow + r) * TK_ + gcol] = pu;
        rs[r] += bf2f(pu);
      }
    }
    #pragma unroll
    for (int r = 0; r < 4; ++r) {
      rs[r] += __shfl_xor(rs[r], 1, 64);
      rs[r] += __shfl_xor(rs[r], 2, 64);
      rs[r] += __shfl_xor(rs[r], 4, 64);
      rs[r] += __shfl_xor(rs[r], 8, 64);
    }
    if (lc == 0) {
      #pragma unroll
      for (int r = 0; r < 4; ++r) atomicAdd(&lz[grow + r], rs[r]);
    }
  }
}

// GEMM2: out = (P Vt^T) / lsum, fp32 out
__global__ __launch_bounds__(512, 2)
void gemm_pv(const ushort* __restrict__ P, const ushort* __restrict__ Vt,
             const float* __restrict__ lsum, float* __restrict__ out) {
  __shared__ short8 ldsv[8192];       // 128 KiB
  char* lds = (char*)ldsv;
  int bx, by, z;
  xcd_coords(bx, by, z);
  const int bm0 = by * 256;
  const int bn0 = bx * 256;

  floatx4 acc[8][4];
  gemm_core8<TK_>(P + (size_t)z * TQ_ * TK_, Vt + (size_t)z * DV_ * TK_,
                  lds, bm0, bn0, acc);

  const int lane = threadIdx.x & 63;
  const int w    = threadIdx.x >> 6;
  const int wm   = w >> 2, wn = w & 3;
  const int lc   = lane & 15, q = lane >> 4;
  float* ob = out + (size_t)z * TQ_ * DV_;
  const float* lz = lsum + z * TQ_;

  #pragma unroll
  for (int mi = 0; mi < 8; ++mi) {
    const int grow = bm0 + wm * 128 + mi * 16 + (q << 2);
    float linv[4];
    #pragma unroll
    for (int r = 0; r < 4; ++r) linv[r] = 1.f / lz[grow + r];
    #pragma unroll
    for (int ni = 0; ni < 4; ++ni) {
      const int gcol = bn0 + wn * 64 + ni * 16 + lc;
      #pragma unroll
      for (int r = 0; r < 4; ++r)
        ob[(size_t)(grow + r) * DV_ + gcol] = acc[mi][ni][r] * linv[r];
    }
  }
}

// ---------------- launch ----------------
// Workspace layout (bytes):
//   qb   @ 0         : 8*2048*1024*2 = 33554432   (Q bf16)
//   ktb  @ 33554432  : 33554432                   (K^T bf16, [TK][D])
//   vtb  @ 67108864  : 33554432                   (V^T bf16, [DV][TK])
//   P    @ 100663296 : 8*2048*2048*2 = 67108864   (exp(tanh(S)) bf16)
//   lsum @ 167772160 : 8*2048*4      = 65536      (softmax denominators)
// Total: 167837696 bytes (~160 MB)

extern "C" void kernel_launch(void* const* d_in, const int* in_sizes, int n_in,
                              void* d_out, int out_size, void* d_ws, size_t ws_size,
                              hipStream_t stream) {
  const float* q    = (const float*)d_in[0];
  const float* k    = (const float*)d_in[1];
  const float* v    = (const float*)d_in[2];
  const float* bias = (const float*)d_in[3];
  float* out = (float*)d_out;

  char* ws = (char*)d_ws;
  ushort* qb   = (ushort*)(ws);
  ushort* ktb  = (ushort*)(ws + 33554432);
  ushort* vtb  = (ushort*)(ws + 67108864);
  ushort* P    = (ushort*)(ws + 100663296);
  float*  lsum = (float*)(ws + 167772160);

  hipMemsetAsync(lsum, 0, B_ * TQ_ * sizeof(float), stream);

  prep<<<dim3(32, 16, 24), dim3(256), 0, stream>>>(q, k, v, qb, ktb, vtb);

  gemm_qk<<<dim3(TK_ / 256, TQ_ / 256, B_), dim3(512), 0, stream>>>(qb, ktb, bias, P, lsum);
  gemm_pv<<<dim3(DV_ / 256, TQ_ / 256, B_), dim3(512), 0, stream>>>(P, vtb, lsum, out);
}